// Round 11
// baseline (156.770 us; speedup 1.0000x reference)
//
#include <hip/hip_runtime.h>

// VectorQuantizer: B=16, D=64, H=64, W=64, K=1024
#define DD 64
#define KK 1024
#define NPTS 65536
#define TOTAL 4194304
#define NBLK_TOTAL 512   // ticket: A(256) + B(256)

// Output layout (flat f32): quantized[4194304], L1, L2, idx[65536]
#define OFF_L1 4194304
#define OFF_L2 4194305
#define OFF_IDX 4194306

// ws layout (bytes): [0] f32 sum, [8] u32 ticket, enh @ float 64 (byte 256),
// ehT @ byte 65536 (128KB), elT @ byte 196608 (128KB). (<=328KB used)
#define WS_ENH_F 64
#define WS_EHT_BYTE 65536
#define WS_ELT_BYTE (65536 + 131072)

// score = dot(x,e) + 512 - ||e||^2/2  (argmax == argmin distance).
// Rescue margin: 64-ulp granule (<=4.6e-3) + bf16x3 err (~6e-4) + slack.
#define MARGIN_S 0.008f

typedef __attribute__((ext_vector_type(8))) short short8;
typedef __attribute__((ext_vector_type(4))) float f32x4;

__device__ __forceinline__ unsigned short bf16_rne(float f) {
    unsigned b = __float_as_uint(f);
    return (unsigned short)((b + 0x7FFFu + ((b >> 16) & 1u)) >> 16);
}
__device__ __forceinline__ float bf16_to_f(unsigned short h) {
    return __uint_as_float(((unsigned)h) << 16);
}
__device__ __forceinline__ unsigned umax(unsigned a, unsigned b) { return a > b ? a : b; }
__device__ __forceinline__ unsigned umin(unsigned a, unsigned b) { return a < b ? a : b; }
// async global->LDS DMA, 16B per lane; LDS dest = wave-uniform base + lane*16
__device__ __forceinline__ void gld_lds16(const void* g, void* l) {
    __builtin_amdgcn_global_load_lds(
        (const __attribute__((address_space(1))) void*)g,
        (__attribute__((address_space(3))) void*)l, 16, 0, 0);
}
// swizzled position of element d within a 64-elem row r (16B-granule XOR key)
__device__ __forceinline__ int swz(int r, int d) {
    return ((d & ~7) ^ ((r & 7) << 3)) | (d & 7);
}

// ---------- kernel 1: enh + swizzled bf16 hi/lo codebook [k][64] ----------
__global__ __launch_bounds__(256) void prep_kernel(const float* __restrict__ e,
                                                   float* __restrict__ enh,
                                                   unsigned short* __restrict__ ehT,
                                                   unsigned short* __restrict__ elT,
                                                   float* __restrict__ sum,
                                                   unsigned* __restrict__ tick) {
    __shared__ unsigned short tH[64 * 64];   // 8KB [code_local][swz d]
    __shared__ unsigned short tL[64 * 64];
    __shared__ float ps[4 * 64];
    const int tid = threadIdx.x, wave = tid >> 6, lane = tid & 63;
    if (blockIdx.x == 0 && tid == 0) { *sum = 0.f; *tick = 0u; }
    const int k = blockIdx.x * 64 + lane;    // this thread's code
    float s2 = 0.f;
    short8 hh[2], ll[2];
#pragma unroll
    for (int g = 0; g < 2; ++g)
#pragma unroll
        for (int j = 0; j < 8; ++j) {
            const int d = wave * 16 + g * 8 + j;
            const float v = e[d * KK + k];   // lanes k-contiguous -> coalesced
            const unsigned short h = bf16_rne(v);
            hh[g][j] = (short)h;
            ll[g][j] = (short)bf16_rne(v - bf16_to_f(h));
            s2 = fmaf(v, v, s2);
        }
    ps[wave * 64 + lane] = s2;
#pragma unroll
    for (int g = 0; g < 2; ++g) {
        const int pos = lane * 64 + ((wave * 16 + g * 8) ^ ((k & 7) << 3));
        *(short8*)(tH + pos) = hh[g];
        *(short8*)(tL + pos) = ll[g];
    }
    __syncthreads();
    if (wave == 0) {
        const float t = ps[lane] + ps[64 + lane] + ps[128 + lane] + ps[192 + lane];
        enh[k] = 512.0f - 0.5f * t;
    }
    {
        const short8* srcH = (const short8*)tH;
        const short8* srcL = (const short8*)tL;
        short8* dstH = (short8*)(ehT + blockIdx.x * 64 * 64);
        short8* dstL = (short8*)(elT + blockIdx.x * 64 * 64);
        dstH[tid * 2]     = srcH[tid * 2];
        dstH[tid * 2 + 1] = srcH[tid * 2 + 1];
        dstL[tid * 2]     = srcL[tid * 2];
        dstL[tid * 2 + 1] = srcL[tid * 2 + 1];
    }
}

// ======================= WITHIN-RUN A/B (r8 method) =======================
// A = r10's validated body (65us full-grid; best measured). B = WAVE-PRIVATE
// streaming: each wave owns 32 pts + its own triple-buffered 16-code tile
// slots, self-paced via per-wave counted vmcnt -- ZERO in-loop barriers.
// Every prior structure kept 4-wave lockstep around a shared tile (the
// untested convoy source). Same container, back-to-back dispatches.

// ---------- kernel 2A: r10 body (control), blocks 0-255 ----------
__global__ __launch_bounds__(256) void vq_gemm_a(const float* __restrict__ x,
                                                 const float* __restrict__ e,
                                                 const float* __restrict__ enh,
                                                 const unsigned short* __restrict__ ehT,
                                                 const unsigned short* __restrict__ elT,
                                                 float* __restrict__ out,
                                                 float* __restrict__ sum,
                                                 unsigned* __restrict__ tick) {
    __shared__ __align__(16) char ebuf[2 * 16384];   // 32KB

    unsigned short* xbh = (unsigned short*)ebuf;
    unsigned short* xbl = (unsigned short*)(ebuf + 16384);
    int*   ks  = (int*)ebuf;
    float* xp  = (float*)(ks + 128);
    int*   rl  = (int*)(xp + 64);
    int*   rn  = rl + 128;
    float* rv  = (float*)(rn + 1);
    int*   ri  = (int*)(rv + 4);
    float* red = (float*)(ri + 4);

    const int tid = threadIdx.x;
    const int wave = tid >> 6, lane = tid & 63;
    const int n0 = blockIdx.x * 128;
    const int b = n0 >> 12;
    const int hw0 = n0 & 4095;

    const char* ehTb = (const char*)ehT;
    const char* elTb = (const char*)elT;
    const int lofs = wave * 1024 + lane * 16;

    {
        const int p = tid & 127, dg = tid >> 7;
        const float* xs = x + ((b * DD + dg * 32) << 12) + hw0 + p;
        float xv[32];
#pragma unroll
        for (int s = 0; s < 32; ++s) xv[s] = xs[s << 12];
#pragma unroll
        for (int g = 0; g < 4; ++g) {
            short8 hh, ll;
#pragma unroll
            for (int j = 0; j < 8; ++j) {
                const float f = xv[g * 8 + j];
                const unsigned short h = bf16_rne(f);
                hh[j] = (short)h;
                ll[j] = (short)bf16_rne(f - bf16_to_f(h));
            }
            const int d0 = dg * 32 + g * 8;
            const int pos = p * 64 + (d0 ^ ((p & 7) << 3));
            *(short8*)(xbh + pos) = hh;
            *(short8*)(xbl + pos) = ll;
        }
    }
    __syncthreads();

    const int ln15 = lane & 15, q8 = (lane >> 4) * 8;
    const int wp = wave * 32;

    short8 ah[2][2], al[2][2];
#pragma unroll
    for (int rf = 0; rf < 2; ++rf)
#pragma unroll
        for (int kc = 0; kc < 2; ++kc) {
            const int pp = wp + rf * 16 + ln15;
            const int pos = pp * 64 + ((kc * 32 + q8) ^ ((pp & 7) << 3));
            ah[rf][kc] = *(const short8*)(xbh + pos);
            al[rf][kc] = *(const short8*)(xbl + pos);
        }
    __syncthreads();

    {
        char* db = ebuf;
        gld_lds16(ehTb + lofs,        db + wave * 1024);
        gld_lds16(ehTb + 4096 + lofs, db + 4096 + wave * 1024);
        gld_lds16(elTb + lofs,        db + 8192 + wave * 1024);
        gld_lds16(elTb + 4096 + lofs, db + 12288 + wave * 1024);
    }

    unsigned v1u[8], v2u[8];
#pragma unroll
    for (int r = 0; r < 8; ++r) { v1u[r] = 0u; v2u[r] = 0u; }

    for (int kt = 0; kt < 16; ++kt) {
        __syncthreads();
        if (kt < 15) {
            const int nkt = kt + 1;
            char* db = ebuf + (nkt & 1) * 16384;
            const char* sH = ehTb + nkt * 8192 + lofs;
            const char* sL = elTb + nkt * 8192 + lofs;
            gld_lds16(sH,        db + wave * 1024);
            gld_lds16(sH + 4096, db + 4096 + wave * 1024);
            gld_lds16(sL,        db + 8192 + wave * 1024);
            gld_lds16(sL + 4096, db + 12288 + wave * 1024);
        }
        const unsigned short* ebH = (const unsigned short*)(ebuf + (kt & 1) * 16384);
        const unsigned short* ebL = ebH + 4096;

        f32x4 acc[2][4];
#pragma unroll
        for (int cf = 0; cf < 4; ++cf) {
            const float ec = enh[kt * 64 + cf * 16 + ln15];
#pragma unroll
            for (int rf = 0; rf < 2; ++rf)
                acc[rf][cf] = (f32x4){ec, ec, ec, ec};
        }

#pragma unroll
        for (int kc = 0; kc < 2; ++kc) {
            short8 bh[4], bl[4];
#pragma unroll
            for (int cf = 0; cf < 4; ++cf) {
                const int c = cf * 16 + ln15;
                const int pos = c * 64 + ((kc * 32 + q8) ^ ((c & 7) << 3));
                bh[cf] = *(const short8*)(ebH + pos);
                bl[cf] = *(const short8*)(ebL + pos);
            }
#pragma unroll
            for (int rf = 0; rf < 2; ++rf)
#pragma unroll
                for (int cf = 0; cf < 4; ++cf) {
                    acc[rf][cf] = __builtin_amdgcn_mfma_f32_16x16x32_bf16(al[rf][kc], bh[cf], acc[rf][cf], 0, 0, 0);
                    acc[rf][cf] = __builtin_amdgcn_mfma_f32_16x16x32_bf16(ah[rf][kc], bl[cf], acc[rf][cf], 0, 0, 0);
                    acc[rf][cf] = __builtin_amdgcn_mfma_f32_16x16x32_bf16(ah[rf][kc], bh[cf], acc[rf][cf], 0, 0, 0);
                }
        }

#pragma unroll
        for (int rf = 0; rf < 2; ++rf)
#pragma unroll
            for (int reg = 0; reg < 4; ++reg) {
                const int r = rf * 4 + reg;
                const unsigned k0 = (__float_as_uint(acc[rf][0][reg]) | 63u) ^ (unsigned)(kt * 4 + 0);
                const unsigned k1 = (__float_as_uint(acc[rf][1][reg]) | 63u) ^ (unsigned)(kt * 4 + 1);
                const unsigned k2 = (__float_as_uint(acc[rf][2][reg]) | 63u) ^ (unsigned)(kt * 4 + 2);
                const unsigned k3 = (__float_as_uint(acc[rf][3][reg]) | 63u) ^ (unsigned)(kt * 4 + 3);
                unsigned a = umax(k0, k1), bb = umin(k0, k1);
                v2u[r] = umax(umax(v2u[r], umin(v1u[r], a)), bb);
                v1u[r] = umax(v1u[r], a);
                a = umax(k2, k3); bb = umin(k2, k3);
                v2u[r] = umax(umax(v2u[r], umin(v1u[r], a)), bb);
                v1u[r] = umax(v1u[r], a);
            }
    }

    __syncthreads();
    if (tid == 0) *rn = 0;
    __syncthreads();

#pragma unroll
    for (int r = 0; r < 8; ++r) {
        const unsigned c6 = 63u - (v1u[r] & 63u);
        int col = (int)(c6 >> 2) * 64 + (int)(c6 & 3) * 16 + ln15;
        float val = __uint_as_float(v1u[r] & ~63u);
        float sec = __uint_as_float(v2u[r] & ~63u);
#pragma unroll
        for (int msk = 1; msk < 16; msk <<= 1) {
            const float ov = __shfl_xor(val, msk);
            const int oc = __shfl_xor(col, msk);
            const float os = __shfl_xor(sec, msk);
            sec = fmaxf(fmaxf(sec, os), fminf(val, ov));
            const bool t = (ov > val) || (ov == val && oc < col);
            val = t ? ov : val;
            col = t ? oc : col;
        }
        if (ln15 == 0) {
            const int qq = lane >> 4;
            const int pt = wp + (r >> 2) * 16 + qq * 4 + (r & 3);
            ks[pt] = col;
            if (val - sec < MARGIN_S) {
                const int w = atomicAdd(rn, 1);
                rl[w] = pt;
            }
        }
    }
    __syncthreads();

    const int lcnt = *rn;
    for (int it = 0; it < lcnt; ++it) {
        const int pr = rl[it];
        if (tid < 64) xp[tid] = x[((b * DD + tid) << 12) + hw0 + pr];
        __syncthreads();
        float d0 = 0.f, d1 = 0.f, d2 = 0.f, d3 = 0.f;
#pragma unroll 8
        for (int dd = 0; dd < DD; ++dd) {
            const float xd = xp[dd];
            const float4 ev = *(const float4*)(e + dd * KK + tid * 4);
            d0 = fmaf(xd, ev.x, d0);
            d1 = fmaf(xd, ev.y, d1);
            d2 = fmaf(xd, ev.z, d2);
            d3 = fmaf(xd, ev.w, d3);
        }
        const float4 ea = *(const float4*)(enh + tid * 4);
        float bs = d0 + ea.x;
        int bi2 = tid * 4;
        if (d1 + ea.y > bs) { bs = d1 + ea.y; bi2 = tid * 4 + 1; }
        if (d2 + ea.z > bs) { bs = d2 + ea.z; bi2 = tid * 4 + 2; }
        if (d3 + ea.w > bs) { bs = d3 + ea.w; bi2 = tid * 4 + 3; }
#pragma unroll
        for (int m = 1; m < 64; m <<= 1) {
            const float ov = __shfl_xor(bs, m, 64);
            const int oi = __shfl_xor(bi2, m, 64);
            if (ov > bs || (ov == bs && oi < bi2)) { bs = ov; bi2 = oi; }
        }
        if (lane == 0) { rv[wave] = bs; ri[wave] = bi2; }
        __syncthreads();
        if (tid == 0) {
            float gs = rv[0];
            int gi = ri[0];
#pragma unroll
            for (int t2 = 1; t2 < 4; ++t2)
                if (rv[t2] > gs || (rv[t2] == gs && ri[t2] < gi)) { gs = rv[t2]; gi = ri[t2]; }
            ks[pr] = gi;
        }
        __syncthreads();
    }

    if (tid < 128) out[OFF_IDX + n0 + tid] = (float)ks[tid];

    {
        const int pe = tid & 127, dh = tid >> 7;
        const int kp = ks[pe];
        float lacc = 0.f;
#pragma unroll
        for (int s = 0; s < 32; ++s) {
            const int d = dh * 32 + s;
            const float qv = e[d * KK + kp];
            const float xv = x[((b * DD + d) << 12) + hw0 + pe];
            out[((b * DD + d) << 12) + hw0 + pe] = qv;
            const float df = xv - qv;
            lacc = fmaf(df, df, lacc);
        }
#pragma unroll
        for (int off = 32; off > 0; off >>= 1) lacc += __shfl_down(lacc, off, 64);
        if (lane == 0) red[wave] = lacc;
    }
    __syncthreads();
    if (tid == 0) {
        atomicAdd(sum, red[0] + red[1] + red[2] + red[3]);
        __threadfence();
        const unsigned old = atomicAdd(tick, 1u);
        if (old == (unsigned)(NBLK_TOTAL - 1)) {
            const float s = atomicAdd(sum, 0.0f);
            const float m = s * (1.0f / (float)TOTAL);
            out[OFF_L1] = m;
            out[OFF_L2] = m;
        }
    }
}

// ---------- kernel 2B: WAVE-PRIVATE streaming, blocks 256-511 ----------
// Each wave: 32 pts x all 1024 codes, streamed as 64 tiles of 16 codes.
// Per-wave TRIPLE-buffered 4KB slots (hi 2KB + lo 2KB), rotating pointers;
// counted s_waitcnt vmcnt(4) -- NO barriers in the loop (only this wave
// reads its slots; vmcnt is per-wave state). enh in LDS (zero other vmcnt
// ops in-loop; __syncthreads before loop drains the prologue ledger).
// vmcnt audit (4 gld/tile): prologue issues T0,T1 (8 out). iter t: wait
// vmcnt(4) -> T(t) done; issue T(t+2) if t<62 (slot (t+2)%3: reader was
// iter t-1, finished in program order); t=63: vmcnt(0).
__global__ __launch_bounds__(256) void vq_gemm_b(const float* __restrict__ x,
                                                 const float* __restrict__ e,
                                                 const float* __restrict__ enh,
                                                 const unsigned short* __restrict__ ehT,
                                                 const unsigned short* __restrict__ elT,
                                                 float* __restrict__ out,
                                                 float* __restrict__ sum,
                                                 unsigned* __restrict__ tick) {
    __shared__ __align__(16) char ebuf[4 * 12288];   // 48KB: 12KB/wave (3x4KB slots)
    __shared__ float enh_lds[1024];                  // 4KB

    unsigned short* xbh = (unsigned short*)ebuf;            // prologue staging
    unsigned short* xbl = (unsigned short*)(ebuf + 16384);
    int*   ks  = (int*)ebuf;            // post-loop aliases (after barrier)
    float* xp  = (float*)(ks + 128);
    int*   rl  = (int*)(xp + 64);
    int*   rn  = rl + 128;
    float* rv  = (float*)(rn + 1);
    int*   ri  = (int*)(rv + 4);
    float* red = (float*)(ri + 4);

    const int tid = threadIdx.x;
    const int wave = tid >> 6, lane = tid & 63;
    const int n0 = (blockIdx.x + 256) * 128;   // second half of points
    const int b = n0 >> 12;
    const int hw0 = n0 & 4095;

    const char* ehTb = (const char*)ehT;
    const char* elTb = (const char*)elT;

    // enh -> LDS (4 floats/thread)
    *(float4*)(enh_lds + tid * 4) = *(const float4*)(enh + tid * 4);

    // x prep (r10 pattern)
    {
        const int p = tid & 127, dg = tid >> 7;
        const float* xs = x + ((b * DD + dg * 32) << 12) + hw0 + p;
        float xv[32];
#pragma unroll
        for (int s = 0; s < 32; ++s) xv[s] = xs[s << 12];
#pragma unroll
        for (int g = 0; g < 4; ++g) {
            short8 hh, ll;
#pragma unroll
            for (int j = 0; j < 8; ++j) {
                const float f = xv[g * 8 + j];
                const unsigned short h = bf16_rne(f);
                hh[j] = (short)h;
                ll[j] = (short)bf16_rne(f - bf16_to_f(h));
            }
            const int d0 = dg * 32 + g * 8;
            const int pos = p * 64 + (d0 ^ ((p & 7) << 3));
            *(short8*)(xbh + pos) = hh;
            *(short8*)(xbl + pos) = ll;
        }
    }
    __syncthreads();

    const int ln15 = lane & 15, q8 = (lane >> 4) * 8;
    const int wp = wave * 32;

    short8 ah[2][2], al[2][2];
#pragma unroll
    for (int rf = 0; rf < 2; ++rf)
#pragma unroll
        for (int kc = 0; kc < 2; ++kc) {
            const int pp = wp + rf * 16 + ln15;
            const int pos = pp * 64 + ((kc * 32 + q8) ^ ((pp & 7) << 3));
            ah[rf][kc] = *(const short8*)(xbh + pos);
            al[rf][kc] = *(const short8*)(xbl + pos);
        }
    __syncthreads();   // drains ALL prologue vm/lgkm ops -> clean vmcnt ledger

    // rotating per-wave slot pointers: r0=slot(t), r1=slot(t+1), r2=slot(t+2)
    char* wbuf = ebuf + wave * 12288;
    char* r0 = wbuf;
    char* r1 = wbuf + 4096;
    char* r2 = wbuf + 8192;
    const char* sHb = ehTb + lane * 16;
    const char* sLb = elTb + lane * 16;

    // ISSUE tile t into dst: hi 2KB at +0, lo 2KB at +2048
#define ISSUE_B(t, dst)                                        \
    {                                                          \
        const char* sH = sHb + (t) * 2048;                     \
        const char* sL = sLb + (t) * 2048;                     \
        gld_lds16(sH,        (dst));                           \
        gld_lds16(sH + 1024, (dst) + 1024);                    \
        gld_lds16(sL,        (dst) + 2048);                    \
        gld_lds16(sL + 1024, (dst) + 3072);                    \
    }

    ISSUE_B(0, r0);
    ISSUE_B(1, r1);

    unsigned v1u[8], v2u[8];
#pragma unroll
    for (int r = 0; r < 8; ++r) { v1u[r] = 0u; v2u[r] = 0u; }

    for (int t = 0; t < 64; ++t) {
        if (t < 63) asm volatile("s_waitcnt vmcnt(4)" ::: "memory");
        else        asm volatile("s_waitcnt vmcnt(0)" ::: "memory");
        if (t < 62) ISSUE_B(t + 2, r2);

        const unsigned short* tbH = (const unsigned short*)r0;
        const unsigned short* tbL = tbH + 1024;   // +2048B

        const float ec = enh_lds[t * 16 + ln15];
        f32x4 acc[2];
        acc[0] = (f32x4){ec, ec, ec, ec};
        acc[1] = acc[0];

#pragma unroll
        for (int kc = 0; kc < 2; ++kc) {
            const int pos = ln15 * 64 + ((kc * 32 + q8) ^ ((ln15 & 7) << 3));
            const short8 bh = *(const short8*)(tbH + pos);
            const short8 bl = *(const short8*)(tbL + pos);
#pragma unroll
            for (int rf = 0; rf < 2; ++rf) {
                acc[rf] = __builtin_amdgcn_mfma_f32_16x16x32_bf16(al[rf][kc], bh, acc[rf], 0, 0, 0);
                acc[rf] = __builtin_amdgcn_mfma_f32_16x16x32_bf16(ah[rf][kc], bl, acc[rf], 0, 0, 0);
                acc[rf] = __builtin_amdgcn_mfma_f32_16x16x32_bf16(ah[rf][kc], bh, acc[rf], 0, 0, 0);
            }
        }

        // key = (bits|63) ^ t  (tie-break toward smaller tile = smaller k)
#pragma unroll
        for (int rf = 0; rf < 2; ++rf)
#pragma unroll
            for (int reg = 0; reg < 4; ++reg) {
                const int r = rf * 4 + reg;
                const unsigned k0 = (__float_as_uint(acc[rf][reg]) | 63u) ^ (unsigned)t;
                v2u[r] = umax(v2u[r], umin(v1u[r], k0));
                v1u[r] = umax(v1u[r], k0);
            }

        char* tmp = r0; r0 = r1; r1 = r2; r2 = tmp;   // rotate slots
    }
#undef ISSUE_B

    __syncthreads();   // all waves past their loops -> ebuf aliases safe
    if (tid == 0) *rn = 0;
    __syncthreads();

    // decode: col = tile*16 + ln15; per-wave final merge over 16-lane groups
#pragma unroll
    for (int r = 0; r < 8; ++r) {
        const unsigned c6 = 63u - (v1u[r] & 63u);
        int col = (int)c6 * 16 + ln15;
        float val = __uint_as_float(v1u[r] & ~63u);
        float sec = __uint_as_float(v2u[r] & ~63u);
#pragma unroll
        for (int msk = 1; msk < 16; msk <<= 1) {
            const float ov = __shfl_xor(val, msk);
            const int oc = __shfl_xor(col, msk);
            const float os = __shfl_xor(sec, msk);
            sec = fmaxf(fmaxf(sec, os), fminf(val, ov));
            const bool t = (ov > val) || (ov == val && oc < col);
            val = t ? ov : val;
            col = t ? oc : col;
        }
        if (ln15 == 0) {
            const int qq = lane >> 4;
            const int pt = wp + (r >> 2) * 16 + qq * 4 + (r & 3);
            ks[pt] = col;
            if (val - sec < MARGIN_S) {
                const int w = atomicAdd(rn, 1);
                rl[w] = pt;
            }
        }
    }
    __syncthreads();

    const int lcnt = *rn;
    for (int it = 0; it < lcnt; ++it) {
        const int pr = rl[it];
        if (tid < 64) xp[tid] = x[((b * DD + tid) << 12) + hw0 + pr];
        __syncthreads();
        float d0 = 0.f, d1 = 0.f, d2 = 0.f, d3 = 0.f;
#pragma unroll 8
        for (int dd = 0; dd < DD; ++dd) {
            const float xd = xp[dd];
            const float4 ev = *(const float4*)(e + dd * KK + tid * 4);
            d0 = fmaf(xd, ev.x, d0);
            d1 = fmaf(xd, ev.y, d1);
            d2 = fmaf(xd, ev.z, d2);
            d3 = fmaf(xd, ev.w, d3);
        }
        const float4 ea = *(const float4*)(enh + tid * 4);
        float bs = d0 + ea.x;
        int bi2 = tid * 4;
        if (d1 + ea.y > bs) { bs = d1 + ea.y; bi2 = tid * 4 + 1; }
        if (d2 + ea.z > bs) { bs = d2 + ea.z; bi2 = tid * 4 + 2; }
        if (d3 + ea.w > bs) { bs = d3 + ea.w; bi2 = tid * 4 + 3; }
#pragma unroll
        for (int m = 1; m < 64; m <<= 1) {
            const float ov = __shfl_xor(bs, m, 64);
            const int oi = __shfl_xor(bi2, m, 64);
            if (ov > bs || (ov == bs && oi < bi2)) { bs = ov; bi2 = oi; }
        }
        if (lane == 0) { rv[wave] = bs; ri[wave] = bi2; }
        __syncthreads();
        if (tid == 0) {
            float gs = rv[0];
            int gi = ri[0];
#pragma unroll
            for (int t2 = 1; t2 < 4; ++t2)
                if (rv[t2] > gs || (rv[t2] == gs && ri[t2] < gi)) { gs = rv[t2]; gi = ri[t2]; }
            ks[pr] = gi;
        }
        __syncthreads();
    }

    if (tid < 128) out[OFF_IDX + n0 + tid] = (float)ks[tid];

    {
        const int pe = tid & 127, dh = tid >> 7;
        const int kp = ks[pe];
        float lacc = 0.f;
#pragma unroll
        for (int s = 0; s < 32; ++s) {
            const int d = dh * 32 + s;
            const float qv = e[d * KK + kp];
            const float xv = x[((b * DD + d) << 12) + hw0 + pe];
            out[((b * DD + d) << 12) + hw0 + pe] = qv;
            const float df = xv - qv;
            lacc = fmaf(df, df, lacc);
        }
#pragma unroll
        for (int off = 32; off > 0; off >>= 1) lacc += __shfl_down(lacc, off, 64);
        if (lane == 0) red[wave] = lacc;
    }
    __syncthreads();
    if (tid == 0) {
        atomicAdd(sum, red[0] + red[1] + red[2] + red[3]);
        __threadfence();
        const unsigned old = atomicAdd(tick, 1u);
        if (old == (unsigned)(NBLK_TOTAL - 1)) {
            const float s = atomicAdd(sum, 0.0f);
            const float m = s * (1.0f / (float)TOTAL);
            out[OFF_L1] = m;
            out[OFF_L2] = m;
        }
    }
}

extern "C" void kernel_launch(void* const* d_in, const int* in_sizes, int n_in,
                              void* d_out, int out_size, void* d_ws, size_t ws_size,
                              hipStream_t stream) {
    const float* x = (const float*)d_in[0];      // [16,64,64,64]
    const float* e = (const float*)d_in[1];      // [64,1024]
    float* out = (float*)d_out;

    float* sum = (float*)d_ws;
    unsigned* tick = (unsigned*)d_ws + 2;
    float* enh = (float*)d_ws + WS_ENH_F;
    unsigned short* ehT = (unsigned short*)((char*)d_ws + WS_EHT_BYTE);
    unsigned short* elT = (unsigned short*)((char*)d_ws + WS_ELT_BYTE);

    prep_kernel<<<KK / 64, 256, 0, stream>>>(e, enh, ehT, elT, sum, tick);
    vq_gemm_a<<<256, 256, 0, stream>>>(x, e, enh, ehT, elT, out, sum, tick);
    vq_gemm_b<<<256, 256, 0, stream>>>(x, e, enh, ehT, elT, out, sum, tick);
}

// Round 12
// 148.493 us; speedup vs baseline: 1.0557x; 1.0557x over previous
//
#include <hip/hip_runtime.h>

// VectorQuantizer: B=16, D=64, H=64, W=64, K=1024
#define DD 64
#define KK 1024
#define NPTS 65536
#define TOTAL 4194304
#define NBLK_TOTAL 512   // ticket: A(256) + B(256)

// Output layout (flat f32): quantized[4194304], L1, L2, idx[65536]
#define OFF_L1 4194304
#define OFF_L2 4194305
#define OFF_IDX 4194306

// ws layout (bytes): [0] f32 sum, [8] u32 ticket, enh @ float 64 (byte 256),
// ehT @ byte 65536 (128KB), elT @ byte 196608 (128KB). (<=328KB used)
#define WS_ENH_F 64
#define WS_EHT_BYTE 65536
#define WS_ELT_BYTE (65536 + 131072)

// score = dot(x,e) + 512 - ||e||^2/2  (argmax == argmin distance).
// Rescue margin: 64-ulp granule (<=4.6e-3) + bf16x3 err (~6e-4) + slack.
#define MARGIN_S 0.008f

typedef __attribute__((ext_vector_type(8))) short short8;
typedef __attribute__((ext_vector_type(4))) float f32x4;

__device__ __forceinline__ unsigned short bf16_rne(float f) {
    unsigned b = __float_as_uint(f);
    return (unsigned short)((b + 0x7FFFu + ((b >> 16) & 1u)) >> 16);
}
__device__ __forceinline__ float bf16_to_f(unsigned short h) {
    return __uint_as_float(((unsigned)h) << 16);
}
__device__ __forceinline__ unsigned umax(unsigned a, unsigned b) { return a > b ? a : b; }
__device__ __forceinline__ unsigned umin(unsigned a, unsigned b) { return a < b ? a : b; }
// async global->LDS DMA, 16B per lane; LDS dest = wave-uniform base + lane*16
__device__ __forceinline__ void gld_lds16(const void* g, void* l) {
    __builtin_amdgcn_global_load_lds(
        (const __attribute__((address_space(1))) void*)g,
        (__attribute__((address_space(3))) void*)l, 16, 0, 0);
}
// swizzled position of element d within a 64-elem row r (16B-granule XOR key)
__device__ __forceinline__ int swz(int r, int d) {
    return ((d & ~7) ^ ((r & 7) << 3)) | (d & 7);
}

// ---------- kernel 1: enh + swizzled bf16 hi/lo codebook [k][64] ----------
__global__ __launch_bounds__(256) void prep_kernel(const float* __restrict__ e,
                                                   float* __restrict__ enh,
                                                   unsigned short* __restrict__ ehT,
                                                   unsigned short* __restrict__ elT,
                                                   float* __restrict__ sum,
                                                   unsigned* __restrict__ tick) {
    __shared__ unsigned short tH[64 * 64];   // 8KB [code_local][swz d]
    __shared__ unsigned short tL[64 * 64];
    __shared__ float ps[4 * 64];
    const int tid = threadIdx.x, wave = tid >> 6, lane = tid & 63;
    if (blockIdx.x == 0 && tid == 0) { *sum = 0.f; *tick = 0u; }
    const int k = blockIdx.x * 64 + lane;    // this thread's code
    float s2 = 0.f;
    short8 hh[2], ll[2];
#pragma unroll
    for (int g = 0; g < 2; ++g)
#pragma unroll
        for (int j = 0; j < 8; ++j) {
            const int d = wave * 16 + g * 8 + j;
            const float v = e[d * KK + k];   // lanes k-contiguous -> coalesced
            const unsigned short h = bf16_rne(v);
            hh[g][j] = (short)h;
            ll[g][j] = (short)bf16_rne(v - bf16_to_f(h));
            s2 = fmaf(v, v, s2);
        }
    ps[wave * 64 + lane] = s2;
#pragma unroll
    for (int g = 0; g < 2; ++g) {
        const int pos = lane * 64 + ((wave * 16 + g * 8) ^ ((k & 7) << 3));
        *(short8*)(tH + pos) = hh[g];
        *(short8*)(tL + pos) = ll[g];
    }
    __syncthreads();
    if (wave == 0) {
        const float t = ps[lane] + ps[64 + lane] + ps[128 + lane] + ps[192 + lane];
        enh[k] = 512.0f - 0.5f * t;
    }
    {
        const short8* srcH = (const short8*)tH;
        const short8* srcL = (const short8*)tL;
        short8* dstH = (short8*)(ehT + blockIdx.x * 64 * 64);
        short8* dstL = (short8*)(elT + blockIdx.x * 64 * 64);
        dstH[tid * 2]     = srcH[tid * 2];
        dstH[tid * 2 + 1] = srcH[tid * 2 + 1];
        dstL[tid * 2]     = srcL[tid * 2];
        dstL[tid * 2 + 1] = srcL[tid * 2 + 1];
    }
}

// ======================= WITHIN-RUN A/B (r8 method) =======================
// r11 retired wave-private streaming (B=62us vs A<61.6 at 256 blocks: tiny
// per-wave tiles expose full L2 latency; shared tiles amortize it). The two
// VALIDATED wins are: (1) r10's traffic x residency corner (128-pt/32KB,
// 65us full-grid), (2) r8's counted-vmcnt >= lockstep at equal residency.
// This round tests their COMBINATION: A = r10 body verbatim; B = r10 +
// 3x16KB triple buffer + counted vmcnt(4) + enh in LDS (52KB -> still
// 2 blocks/CU at grid 512: residency-clean comparison).

// ---------- kernel 2A: r10 body (control), blocks 0-255 ----------
__global__ __launch_bounds__(256) void vq_gemm_a(const float* __restrict__ x,
                                                 const float* __restrict__ e,
                                                 const float* __restrict__ enh,
                                                 const unsigned short* __restrict__ ehT,
                                                 const unsigned short* __restrict__ elT,
                                                 float* __restrict__ out,
                                                 float* __restrict__ sum,
                                                 unsigned* __restrict__ tick) {
    __shared__ __align__(16) char ebuf[2 * 16384];   // 32KB

    unsigned short* xbh = (unsigned short*)ebuf;
    unsigned short* xbl = (unsigned short*)(ebuf + 16384);
    int*   ks  = (int*)ebuf;
    float* xp  = (float*)(ks + 128);
    int*   rl  = (int*)(xp + 64);
    int*   rn  = rl + 128;
    float* rv  = (float*)(rn + 1);
    int*   ri  = (int*)(rv + 4);
    float* red = (float*)(ri + 4);

    const int tid = threadIdx.x;
    const int wave = tid >> 6, lane = tid & 63;
    const int n0 = blockIdx.x * 128;
    const int b = n0 >> 12;
    const int hw0 = n0 & 4095;

    const char* ehTb = (const char*)ehT;
    const char* elTb = (const char*)elT;
    const int lofs = wave * 1024 + lane * 16;

    {
        const int p = tid & 127, dg = tid >> 7;
        const float* xs = x + ((b * DD + dg * 32) << 12) + hw0 + p;
        float xv[32];
#pragma unroll
        for (int s = 0; s < 32; ++s) xv[s] = xs[s << 12];
#pragma unroll
        for (int g = 0; g < 4; ++g) {
            short8 hh, ll;
#pragma unroll
            for (int j = 0; j < 8; ++j) {
                const float f = xv[g * 8 + j];
                const unsigned short h = bf16_rne(f);
                hh[j] = (short)h;
                ll[j] = (short)bf16_rne(f - bf16_to_f(h));
            }
            const int d0 = dg * 32 + g * 8;
            const int pos = p * 64 + (d0 ^ ((p & 7) << 3));
            *(short8*)(xbh + pos) = hh;
            *(short8*)(xbl + pos) = ll;
        }
    }
    __syncthreads();

    const int ln15 = lane & 15, q8 = (lane >> 4) * 8;
    const int wp = wave * 32;

    short8 ah[2][2], al[2][2];
#pragma unroll
    for (int rf = 0; rf < 2; ++rf)
#pragma unroll
        for (int kc = 0; kc < 2; ++kc) {
            const int pp = wp + rf * 16 + ln15;
            const int pos = pp * 64 + ((kc * 32 + q8) ^ ((pp & 7) << 3));
            ah[rf][kc] = *(const short8*)(xbh + pos);
            al[rf][kc] = *(const short8*)(xbl + pos);
        }
    __syncthreads();

    {
        char* db = ebuf;
        gld_lds16(ehTb + lofs,        db + wave * 1024);
        gld_lds16(ehTb + 4096 + lofs, db + 4096 + wave * 1024);
        gld_lds16(elTb + lofs,        db + 8192 + wave * 1024);
        gld_lds16(elTb + 4096 + lofs, db + 12288 + wave * 1024);
    }

    unsigned v1u[8], v2u[8];
#pragma unroll
    for (int r = 0; r < 8; ++r) { v1u[r] = 0u; v2u[r] = 0u; }

    for (int kt = 0; kt < 16; ++kt) {
        __syncthreads();
        if (kt < 15) {
            const int nkt = kt + 1;
            char* db = ebuf + (nkt & 1) * 16384;
            const char* sH = ehTb + nkt * 8192 + lofs;
            const char* sL = elTb + nkt * 8192 + lofs;
            gld_lds16(sH,        db + wave * 1024);
            gld_lds16(sH + 4096, db + 4096 + wave * 1024);
            gld_lds16(sL,        db + 8192 + wave * 1024);
            gld_lds16(sL + 4096, db + 12288 + wave * 1024);
        }
        const unsigned short* ebH = (const unsigned short*)(ebuf + (kt & 1) * 16384);
        const unsigned short* ebL = ebH + 4096;

        f32x4 acc[2][4];
#pragma unroll
        for (int cf = 0; cf < 4; ++cf) {
            const float ec = enh[kt * 64 + cf * 16 + ln15];
#pragma unroll
            for (int rf = 0; rf < 2; ++rf)
                acc[rf][cf] = (f32x4){ec, ec, ec, ec};
        }

#pragma unroll
        for (int kc = 0; kc < 2; ++kc) {
            short8 bh[4], bl[4];
#pragma unroll
            for (int cf = 0; cf < 4; ++cf) {
                const int c = cf * 16 + ln15;
                const int pos = c * 64 + ((kc * 32 + q8) ^ ((c & 7) << 3));
                bh[cf] = *(const short8*)(ebH + pos);
                bl[cf] = *(const short8*)(ebL + pos);
            }
#pragma unroll
            for (int rf = 0; rf < 2; ++rf)
#pragma unroll
                for (int cf = 0; cf < 4; ++cf) {
                    acc[rf][cf] = __builtin_amdgcn_mfma_f32_16x16x32_bf16(al[rf][kc], bh[cf], acc[rf][cf], 0, 0, 0);
                    acc[rf][cf] = __builtin_amdgcn_mfma_f32_16x16x32_bf16(ah[rf][kc], bl[cf], acc[rf][cf], 0, 0, 0);
                    acc[rf][cf] = __builtin_amdgcn_mfma_f32_16x16x32_bf16(ah[rf][kc], bh[cf], acc[rf][cf], 0, 0, 0);
                }
        }

#pragma unroll
        for (int rf = 0; rf < 2; ++rf)
#pragma unroll
            for (int reg = 0; reg < 4; ++reg) {
                const int r = rf * 4 + reg;
                const unsigned k0 = (__float_as_uint(acc[rf][0][reg]) | 63u) ^ (unsigned)(kt * 4 + 0);
                const unsigned k1 = (__float_as_uint(acc[rf][1][reg]) | 63u) ^ (unsigned)(kt * 4 + 1);
                const unsigned k2 = (__float_as_uint(acc[rf][2][reg]) | 63u) ^ (unsigned)(kt * 4 + 2);
                const unsigned k3 = (__float_as_uint(acc[rf][3][reg]) | 63u) ^ (unsigned)(kt * 4 + 3);
                unsigned a = umax(k0, k1), bb = umin(k0, k1);
                v2u[r] = umax(umax(v2u[r], umin(v1u[r], a)), bb);
                v1u[r] = umax(v1u[r], a);
                a = umax(k2, k3); bb = umin(k2, k3);
                v2u[r] = umax(umax(v2u[r], umin(v1u[r], a)), bb);
                v1u[r] = umax(v1u[r], a);
            }
    }

    __syncthreads();
    if (tid == 0) *rn = 0;
    __syncthreads();

#pragma unroll
    for (int r = 0; r < 8; ++r) {
        const unsigned c6 = 63u - (v1u[r] & 63u);
        int col = (int)(c6 >> 2) * 64 + (int)(c6 & 3) * 16 + ln15;
        float val = __uint_as_float(v1u[r] & ~63u);
        float sec = __uint_as_float(v2u[r] & ~63u);
#pragma unroll
        for (int msk = 1; msk < 16; msk <<= 1) {
            const float ov = __shfl_xor(val, msk);
            const int oc = __shfl_xor(col, msk);
            const float os = __shfl_xor(sec, msk);
            sec = fmaxf(fmaxf(sec, os), fminf(val, ov));
            const bool t = (ov > val) || (ov == val && oc < col);
            val = t ? ov : val;
            col = t ? oc : col;
        }
        if (ln15 == 0) {
            const int qq = lane >> 4;
            const int pt = wp + (r >> 2) * 16 + qq * 4 + (r & 3);
            ks[pt] = col;
            if (val - sec < MARGIN_S) {
                const int w = atomicAdd(rn, 1);
                rl[w] = pt;
            }
        }
    }
    __syncthreads();

    const int lcnt = *rn;
    for (int it = 0; it < lcnt; ++it) {
        const int pr = rl[it];
        if (tid < 64) xp[tid] = x[((b * DD + tid) << 12) + hw0 + pr];
        __syncthreads();
        float d0 = 0.f, d1 = 0.f, d2 = 0.f, d3 = 0.f;
#pragma unroll 8
        for (int dd = 0; dd < DD; ++dd) {
            const float xd = xp[dd];
            const float4 ev = *(const float4*)(e + dd * KK + tid * 4);
            d0 = fmaf(xd, ev.x, d0);
            d1 = fmaf(xd, ev.y, d1);
            d2 = fmaf(xd, ev.z, d2);
            d3 = fmaf(xd, ev.w, d3);
        }
        const float4 ea = *(const float4*)(enh + tid * 4);
        float bs = d0 + ea.x;
        int bi2 = tid * 4;
        if (d1 + ea.y > bs) { bs = d1 + ea.y; bi2 = tid * 4 + 1; }
        if (d2 + ea.z > bs) { bs = d2 + ea.z; bi2 = tid * 4 + 2; }
        if (d3 + ea.w > bs) { bs = d3 + ea.w; bi2 = tid * 4 + 3; }
#pragma unroll
        for (int m = 1; m < 64; m <<= 1) {
            const float ov = __shfl_xor(bs, m, 64);
            const int oi = __shfl_xor(bi2, m, 64);
            if (ov > bs || (ov == bs && oi < bi2)) { bs = ov; bi2 = oi; }
        }
        if (lane == 0) { rv[wave] = bs; ri[wave] = bi2; }
        __syncthreads();
        if (tid == 0) {
            float gs = rv[0];
            int gi = ri[0];
#pragma unroll
            for (int t2 = 1; t2 < 4; ++t2)
                if (rv[t2] > gs || (rv[t2] == gs && ri[t2] < gi)) { gs = rv[t2]; gi = ri[t2]; }
            ks[pr] = gi;
        }
        __syncthreads();
    }

    if (tid < 128) out[OFF_IDX + n0 + tid] = (float)ks[tid];

    {
        const int pe = tid & 127, dh = tid >> 7;
        const int kp = ks[pe];
        float lacc = 0.f;
#pragma unroll
        for (int s = 0; s < 32; ++s) {
            const int d = dh * 32 + s;
            const float qv = e[d * KK + kp];
            const float xv = x[((b * DD + d) << 12) + hw0 + pe];
            out[((b * DD + d) << 12) + hw0 + pe] = qv;
            const float df = xv - qv;
            lacc = fmaf(df, df, lacc);
        }
#pragma unroll
        for (int off = 32; off > 0; off >>= 1) lacc += __shfl_down(lacc, off, 64);
        if (lane == 0) red[wave] = lacc;
    }
    __syncthreads();
    if (tid == 0) {
        atomicAdd(sum, red[0] + red[1] + red[2] + red[3]);
        __threadfence();
        const unsigned old = atomicAdd(tick, 1u);
        if (old == (unsigned)(NBLK_TOTAL - 1)) {
            const float s = atomicAdd(sum, 0.0f);
            const float m = s * (1.0f / (float)TOTAL);
            out[OFF_L1] = m;
            out[OFF_L2] = m;
        }
    }
}

// ---------- kernel 2B: r10 + counted-vmcnt triple-buffer, blocks 256-511 ----------
// Same 128-pt tile math as A; loop converted to the r8-B pattern:
// 3x16KB slots, DMA(kt+2) issued after barrier(kt) into slot (kt+2)%3
// (= slot (kt-1)%3, whose readers finished compute(kt-1) before arriving
// at barrier(kt)); counted s_waitcnt vmcnt(4) -- never 0 mid-loop -- +
// raw s_barrier; NO sched_barrier; enh in LDS (zero other vm ops in-loop).
// Ledger (4 gld/tile/wave): prologue issues DMA(0),DMA(1) after the frag
// barrier (all prior global loads consumed in prologue -> 8 outstanding).
// iter kt<15: wait vmcnt(4) -> DMA(kt) done; kt<14: issue DMA(kt+2).
// kt=14 wait: {DMA14,DMA15}=8 -> vmcnt(4) completes DMA14. kt=15: vmcnt(0).
__global__ __launch_bounds__(256) void vq_gemm_b(const float* __restrict__ x,
                                                 const float* __restrict__ e,
                                                 const float* __restrict__ enh,
                                                 const unsigned short* __restrict__ ehT,
                                                 const unsigned short* __restrict__ elT,
                                                 float* __restrict__ out,
                                                 float* __restrict__ sum,
                                                 unsigned* __restrict__ tick) {
    __shared__ __align__(16) char ebuf[3 * 16384];   // 48KB triple buffer
    __shared__ float enh_lds[1024];                  // 4KB

    unsigned short* xbh = (unsigned short*)ebuf;            // prologue staging
    unsigned short* xbl = (unsigned short*)(ebuf + 16384);
    int*   ks  = (int*)ebuf;            // post-loop aliases (after barrier)
    float* xp  = (float*)(ks + 128);
    int*   rl  = (int*)(xp + 64);
    int*   rn  = rl + 128;
    float* rv  = (float*)(rn + 1);
    int*   ri  = (int*)(rv + 4);
    float* red = (float*)(ri + 4);

    const int tid = threadIdx.x;
    const int wave = tid >> 6, lane = tid & 63;
    const int n0 = (blockIdx.x + 256) * 128;   // second half of points
    const int b = n0 >> 12;
    const int hw0 = n0 & 4095;

    const char* ehTb = (const char*)ehT;
    const char* elTb = (const char*)elT;
    const int lofs = wave * 1024 + lane * 16;

    // enh -> LDS (4 floats/thread; consumed in prologue by ds_write)
    *(float4*)(enh_lds + tid * 4) = *(const float4*)(enh + tid * 4);

    // x prep (r10 pattern, staged in ebuf slots 0-1)
    {
        const int p = tid & 127, dg = tid >> 7;
        const float* xs = x + ((b * DD + dg * 32) << 12) + hw0 + p;
        float xv[32];
#pragma unroll
        for (int s = 0; s < 32; ++s) xv[s] = xs[s << 12];
#pragma unroll
        for (int g = 0; g < 4; ++g) {
            short8 hh, ll;
#pragma unroll
            for (int j = 0; j < 8; ++j) {
                const float f = xv[g * 8 + j];
                const unsigned short h = bf16_rne(f);
                hh[j] = (short)h;
                ll[j] = (short)bf16_rne(f - bf16_to_f(h));
            }
            const int d0 = dg * 32 + g * 8;
            const int pos = p * 64 + (d0 ^ ((p & 7) << 3));
            *(short8*)(xbh + pos) = hh;
            *(short8*)(xbl + pos) = ll;
        }
    }
    __syncthreads();

    const int ln15 = lane & 15, q8 = (lane >> 4) * 8;
    const int wp = wave * 32;

    short8 ah[2][2], al[2][2];
#pragma unroll
    for (int rf = 0; rf < 2; ++rf)
#pragma unroll
        for (int kc = 0; kc < 2; ++kc) {
            const int pp = wp + rf * 16 + ln15;
            const int pos = pp * 64 + ((kc * 32 + q8) ^ ((pp & 7) << 3));
            ah[rf][kc] = *(const short8*)(xbh + pos);
            al[rf][kc] = *(const short8*)(xbl + pos);
        }
    __syncthreads();   // frags in regs everywhere; all 3 slots free; vm ledger clean

    // DMA(0)->slot0, DMA(1)->slot1 (the only outstanding vm ops: 8)
#pragma unroll
    for (int t0 = 0; t0 < 2; ++t0) {
        char* db = ebuf + t0 * 16384;
        const char* sH = ehTb + t0 * 8192 + lofs;
        const char* sL = elTb + t0 * 8192 + lofs;
        gld_lds16(sH,        db + wave * 1024);
        gld_lds16(sH + 4096, db + 4096 + wave * 1024);
        gld_lds16(sL,        db + 8192 + wave * 1024);
        gld_lds16(sL + 4096, db + 12288 + wave * 1024);
    }

    unsigned v1u[8], v2u[8];
#pragma unroll
    for (int r = 0; r < 8; ++r) { v1u[r] = 0u; v2u[r] = 0u; }

    for (int kt = 0; kt < 16; ++kt) {
        if (kt < 15) asm volatile("s_waitcnt vmcnt(4)" ::: "memory");
        else         asm volatile("s_waitcnt vmcnt(0)" ::: "memory");
        __builtin_amdgcn_s_barrier();   // all waves' DMA(kt) landed; slot (kt+2)%3 readers done
        if (kt < 14) {
            const int nkt = kt + 2;
            char* db = ebuf + (nkt % 3) * 16384;
            const char* sH = ehTb + nkt * 8192 + lofs;
            const char* sL = elTb + nkt * 8192 + lofs;
            gld_lds16(sH,        db + wave * 1024);
            gld_lds16(sH + 4096, db + 4096 + wave * 1024);
            gld_lds16(sL,        db + 8192 + wave * 1024);
            gld_lds16(sL + 4096, db + 12288 + wave * 1024);
        }
        const unsigned short* ebH = (const unsigned short*)(ebuf + (kt % 3) * 16384);
        const unsigned short* ebL = ebH + 4096;

        f32x4 acc[2][4];
#pragma unroll
        for (int cf = 0; cf < 4; ++cf) {
            const float ec = enh_lds[kt * 64 + cf * 16 + ln15];
#pragma unroll
            for (int rf = 0; rf < 2; ++rf)
                acc[rf][cf] = (f32x4){ec, ec, ec, ec};
        }

#pragma unroll
        for (int kc = 0; kc < 2; ++kc) {
            short8 bh[4], bl[4];
#pragma unroll
            for (int cf = 0; cf < 4; ++cf) {
                const int c = cf * 16 + ln15;
                const int pos = c * 64 + ((kc * 32 + q8) ^ ((c & 7) << 3));
                bh[cf] = *(const short8*)(ebH + pos);
                bl[cf] = *(const short8*)(ebL + pos);
            }
#pragma unroll
            for (int rf = 0; rf < 2; ++rf)
#pragma unroll
                for (int cf = 0; cf < 4; ++cf) {
                    acc[rf][cf] = __builtin_amdgcn_mfma_f32_16x16x32_bf16(al[rf][kc], bh[cf], acc[rf][cf], 0, 0, 0);
                    acc[rf][cf] = __builtin_amdgcn_mfma_f32_16x16x32_bf16(ah[rf][kc], bl[cf], acc[rf][cf], 0, 0, 0);
                    acc[rf][cf] = __builtin_amdgcn_mfma_f32_16x16x32_bf16(ah[rf][kc], bh[cf], acc[rf][cf], 0, 0, 0);
                }
        }

#pragma unroll
        for (int rf = 0; rf < 2; ++rf)
#pragma unroll
            for (int reg = 0; reg < 4; ++reg) {
                const int r = rf * 4 + reg;
                const unsigned k0 = (__float_as_uint(acc[rf][0][reg]) | 63u) ^ (unsigned)(kt * 4 + 0);
                const unsigned k1 = (__float_as_uint(acc[rf][1][reg]) | 63u) ^ (unsigned)(kt * 4 + 1);
                const unsigned k2 = (__float_as_uint(acc[rf][2][reg]) | 63u) ^ (unsigned)(kt * 4 + 2);
                const unsigned k3 = (__float_as_uint(acc[rf][3][reg]) | 63u) ^ (unsigned)(kt * 4 + 3);
                unsigned a = umax(k0, k1), bb = umin(k0, k1);
                v2u[r] = umax(umax(v2u[r], umin(v1u[r], a)), bb);
                v1u[r] = umax(v1u[r], a);
                a = umax(k2, k3); bb = umin(k2, k3);
                v2u[r] = umax(umax(v2u[r], umin(v1u[r], a)), bb);
                v1u[r] = umax(v1u[r], a);
            }
    }

    __syncthreads();   // all waves done with tile 15 -> ebuf aliases safe
    if (tid == 0) *rn = 0;
    __syncthreads();

#pragma unroll
    for (int r = 0; r < 8; ++r) {
        const unsigned c6 = 63u - (v1u[r] & 63u);
        int col = (int)(c6 >> 2) * 64 + (int)(c6 & 3) * 16 + ln15;
        float val = __uint_as_float(v1u[r] & ~63u);
        float sec = __uint_as_float(v2u[r] & ~63u);
#pragma unroll
        for (int msk = 1; msk < 16; msk <<= 1) {
            const float ov = __shfl_xor(val, msk);
            const int oc = __shfl_xor(col, msk);
            const float os = __shfl_xor(sec, msk);
            sec = fmaxf(fmaxf(sec, os), fminf(val, ov));
            const bool t = (ov > val) || (ov == val && oc < col);
            val = t ? ov : val;
            col = t ? oc : col;
        }
        if (ln15 == 0) {
            const int qq = lane >> 4;
            const int pt = wp + (r >> 2) * 16 + qq * 4 + (r & 3);
            ks[pt] = col;
            if (val - sec < MARGIN_S) {
                const int w = atomicAdd(rn, 1);
                rl[w] = pt;
            }
        }
    }
    __syncthreads();

    const int lcnt = *rn;
    for (int it = 0; it < lcnt; ++it) {
        const int pr = rl[it];
        if (tid < 64) xp[tid] = x[((b * DD + tid) << 12) + hw0 + pr];
        __syncthreads();
        float d0 = 0.f, d1 = 0.f, d2 = 0.f, d3 = 0.f;
#pragma unroll 8
        for (int dd = 0; dd < DD; ++dd) {
            const float xd = xp[dd];
            const float4 ev = *(const float4*)(e + dd * KK + tid * 4);
            d0 = fmaf(xd, ev.x, d0);
            d1 = fmaf(xd, ev.y, d1);
            d2 = fmaf(xd, ev.z, d2);
            d3 = fmaf(xd, ev.w, d3);
        }
        const float4 ea = *(const float4*)(enh + tid * 4);
        float bs = d0 + ea.x;
        int bi2 = tid * 4;
        if (d1 + ea.y > bs) { bs = d1 + ea.y; bi2 = tid * 4 + 1; }
        if (d2 + ea.z > bs) { bs = d2 + ea.z; bi2 = tid * 4 + 2; }
        if (d3 + ea.w > bs) { bs = d3 + ea.w; bi2 = tid * 4 + 3; }
#pragma unroll
        for (int m = 1; m < 64; m <<= 1) {
            const float ov = __shfl_xor(bs, m, 64);
            const int oi = __shfl_xor(bi2, m, 64);
            if (ov > bs || (ov == bs && oi < bi2)) { bs = ov; bi2 = oi; }
        }
        if (lane == 0) { rv[wave] = bs; ri[wave] = bi2; }
        __syncthreads();
        if (tid == 0) {
            float gs = rv[0];
            int gi = ri[0];
#pragma unroll
            for (int t2 = 1; t2 < 4; ++t2)
                if (rv[t2] > gs || (rv[t2] == gs && ri[t2] < gi)) { gs = rv[t2]; gi = ri[t2]; }
            ks[pr] = gi;
        }
        __syncthreads();
    }

    if (tid < 128) out[OFF_IDX + n0 + tid] = (float)ks[tid];

    {
        const int pe = tid & 127, dh = tid >> 7;
        const int kp = ks[pe];
        float lacc = 0.f;
#pragma unroll
        for (int s = 0; s < 32; ++s) {
            const int d = dh * 32 + s;
            const float qv = e[d * KK + kp];
            const float xv = x[((b * DD + d) << 12) + hw0 + pe];
            out[((b * DD + d) << 12) + hw0 + pe] = qv;
            const float df = xv - qv;
            lacc = fmaf(df, df, lacc);
        }
#pragma unroll
        for (int off = 32; off > 0; off >>= 1) lacc += __shfl_down(lacc, off, 64);
        if (lane == 0) red[wave] = lacc;
    }
    __syncthreads();
    if (tid == 0) {
        atomicAdd(sum, red[0] + red[1] + red[2] + red[3]);
        __threadfence();
        const unsigned old = atomicAdd(tick, 1u);
        if (old == (unsigned)(NBLK_TOTAL - 1)) {
            const float s = atomicAdd(sum, 0.0f);
            const float m = s * (1.0f / (float)TOTAL);
            out[OFF_L1] = m;
            out[OFF_L2] = m;
        }
    }
}

extern "C" void kernel_launch(void* const* d_in, const int* in_sizes, int n_in,
                              void* d_out, int out_size, void* d_ws, size_t ws_size,
                              hipStream_t stream) {
    const float* x = (const float*)d_in[0];      // [16,64,64,64]
    const float* e = (const float*)d_in[1];      // [64,1024]
    float* out = (float*)d_out;

    float* sum = (float*)d_ws;
    unsigned* tick = (unsigned*)d_ws + 2;
    float* enh = (float*)d_ws + WS_ENH_F;
    unsigned short* ehT = (unsigned short*)((char*)d_ws + WS_EHT_BYTE);
    unsigned short* elT = (unsigned short*)((char*)d_ws + WS_ELT_BYTE);

    prep_kernel<<<KK / 64, 256, 0, stream>>>(e, enh, ehT, elT, sum, tick);
    vq_gemm_a<<<256, 256, 0, stream>>>(x, e, enh, ehT, elT, out, sum, tick);
    vq_gemm_b<<<256, 256, 0, stream>>>(x, e, enh, ehT, elT, out, sum, tick);
}

// Round 13
// 122.240 us; speedup vs baseline: 1.2825x; 1.2148x over previous
//
#include <hip/hip_runtime.h>

// VectorQuantizer: B=16, D=64, H=64, W=64, K=1024
#define DD 64
#define KK 1024
#define NPTS 65536
#define TOTAL 4194304
#define NBLK_TOTAL 512   // gemm grid = ticket target

// Output layout (flat f32): quantized[4194304], L1, L2, idx[65536]
#define OFF_L1 4194304
#define OFF_L2 4194305
#define OFF_IDX 4194306

// ws layout (bytes): [0] f32 sum, [8] u32 ticket, enh @ float 64 (byte 256),
// ehT @ byte 65536 (128KB), elT @ byte 196608 (128KB). (<=328KB used)
#define WS_ENH_F 64
#define WS_EHT_BYTE 65536
#define WS_ELT_BYTE (65536 + 131072)

// score = dot(x,e) + 512 - ||e||^2/2  (argmax == argmin distance).
// Rescue margin: 64-ulp granule (<=4.6e-3) + bf16x3 err (~6e-4) + slack.
#define MARGIN_S 0.008f

typedef __attribute__((ext_vector_type(8))) short short8;
typedef __attribute__((ext_vector_type(4))) float f32x4;

__device__ __forceinline__ unsigned short bf16_rne(float f) {
    unsigned b = __float_as_uint(f);
    return (unsigned short)((b + 0x7FFFu + ((b >> 16) & 1u)) >> 16);
}
__device__ __forceinline__ float bf16_to_f(unsigned short h) {
    return __uint_as_float(((unsigned)h) << 16);
}
__device__ __forceinline__ unsigned umax(unsigned a, unsigned b) { return a > b ? a : b; }
__device__ __forceinline__ unsigned umin(unsigned a, unsigned b) { return a < b ? a : b; }
// async global->LDS DMA, 16B per lane; LDS dest = wave-uniform base + lane*16
__device__ __forceinline__ void gld_lds16(const void* g, void* l) {
    __builtin_amdgcn_global_load_lds(
        (const __attribute__((address_space(1))) void*)g,
        (__attribute__((address_space(3))) void*)l, 16, 0, 0);
}
// swizzled position of element d within a 64-elem row r (16B-granule XOR key)
__device__ __forceinline__ int swz(int r, int d) {
    return ((d & ~7) ^ ((r & 7) << 3)) | (d & 7);
}

// ---------- kernel 1: enh + swizzled bf16 hi/lo codebook [k][64] ----------
__global__ __launch_bounds__(256) void prep_kernel(const float* __restrict__ e,
                                                   float* __restrict__ enh,
                                                   unsigned short* __restrict__ ehT,
                                                   unsigned short* __restrict__ elT,
                                                   float* __restrict__ sum,
                                                   unsigned* __restrict__ tick) {
    __shared__ unsigned short tH[64 * 64];   // 8KB [code_local][swz d]
    __shared__ unsigned short tL[64 * 64];
    __shared__ float ps[4 * 64];
    const int tid = threadIdx.x, wave = tid >> 6, lane = tid & 63;
    if (blockIdx.x == 0 && tid == 0) { *sum = 0.f; *tick = 0u; }
    const int k = blockIdx.x * 64 + lane;    // this thread's code
    float s2 = 0.f;
    short8 hh[2], ll[2];
#pragma unroll
    for (int g = 0; g < 2; ++g)
#pragma unroll
        for (int j = 0; j < 8; ++j) {
            const int d = wave * 16 + g * 8 + j;
            const float v = e[d * KK + k];   // lanes k-contiguous -> coalesced
            const unsigned short h = bf16_rne(v);
            hh[g][j] = (short)h;
            ll[g][j] = (short)bf16_rne(v - bf16_to_f(h));
            s2 = fmaf(v, v, s2);
        }
    ps[wave * 64 + lane] = s2;
#pragma unroll
    for (int g = 0; g < 2; ++g) {
        const int pos = lane * 64 + ((wave * 16 + g * 8) ^ ((k & 7) << 3));
        *(short8*)(tH + pos) = hh[g];
        *(short8*)(tL + pos) = ll[g];
    }
    __syncthreads();
    if (wave == 0) {
        const float t = ps[lane] + ps[64 + lane] + ps[128 + lane] + ps[192 + lane];
        enh[k] = 512.0f - 0.5f * t;
    }
    {
        const short8* srcH = (const short8*)tH;
        const short8* srcL = (const short8*)tL;
        short8* dstH = (short8*)(ehT + blockIdx.x * 64 * 64);
        short8* dstL = (short8*)(elT + blockIdx.x * 64 * 64);
        dstH[tid * 2]     = srcH[tid * 2];
        dstH[tid * 2 + 1] = srcH[tid * 2 + 1];
        dstL[tid * 2]     = srcL[tid * 2];
        dstL[tid * 2 + 1] = srcL[tid * 2 + 1];
    }
}

// ---------- kernel 2: 512-thread / 8-wave blocks, 128 pts, grid 512 ----------
// THE TLP ROUND. r12 scaling pair: 1 blk/CU (1 wave/SIMD) = 46us half-work;
// 2 blk/CU (2 waves/SIMD, r10) = 65us full-work -> latency-bound, strongly
// sublinear in TLP. r12 A/B also showed counted-vmcnt == __syncthreads
// (retired). This kernel doubles waves/SIMD AT THE SAME TRAFFIC: 8 waves x
// 16 pts each (vs 4 x 32), grid 512 -> 2 blocks/CU = 16 waves/CU = 4/SIMD.
// Per-wave regs halve (~70 VGPR): ah/al[2], acc[4], v1u[4]. enh in LDS
// (kills in-loop global-load latency; r12-B: neutral-at-worst). LDS 36KB.
// Hot loop keeps the validated per-tile __syncthreads double-buffer.
__global__ __launch_bounds__(512) void vq_gemm(const float* __restrict__ x,
                                               const float* __restrict__ e,
                                               const float* __restrict__ enh,
                                               const unsigned short* __restrict__ ehT,
                                               const unsigned short* __restrict__ elT,
                                               float* __restrict__ out,
                                               float* __restrict__ sum,
                                               unsigned* __restrict__ tick) {
    __shared__ __align__(16) char ebuf[2 * 16384];   // 32KB double buffer
    __shared__ float enh_lds[1024];                  // 4KB bias table

    // prologue x-staging aliases (dead once frags are in regs)
    unsigned short* xbh = (unsigned short*)ebuf;            // 16KB [128 pt][64 d] hi
    unsigned short* xbl = (unsigned short*)(ebuf + 16384);  // 16KB lo
    // post-loop aliases into buf0 (written only after the post-loop barrier)
    int*   ks  = (int*)ebuf;            // [128] chosen code per point
    float* xp  = (float*)(ks + 128);    // [64]  rescue point (fp32)
    int*   rl  = (int*)(xp + 64);       // [128] ambiguous-point list
    int*   rn  = rl + 128;              // [1]
    float* rv  = (float*)(rn + 1);      // [8]
    int*   ri  = (int*)(rv + 8);        // [8]
    float* red = (float*)(ri + 8);      // [8]

    const int tid = threadIdx.x;
    const int wave = tid >> 6, lane = tid & 63;   // 8 waves
    const int n0 = blockIdx.x * 128;
    const int b = n0 >> 12;
    const int hw0 = n0 & 4095;

    const char* ehTb = (const char*)ehT;
    const char* elTb = (const char*)elT;

    // enh -> LDS (2 floats/thread)
    *(float2*)(enh_lds + tid * 2) = *(const float2*)(enh + tid * 2);

    // ---- x prep: coalesced global->reg, bf16 hi/lo pack into ebuf.
    // thread t: point p = t&127, d-quarter dg = t>>7 (16 d's each).
    {
        const int p = tid & 127, dg = tid >> 7;
        const float* xs = x + ((b * DD + dg * 16) << 12) + hw0 + p;
        float xv[16];
#pragma unroll
        for (int s = 0; s < 16; ++s) xv[s] = xs[s << 12];   // 512B coalesced rows
#pragma unroll
        for (int g = 0; g < 2; ++g) {
            short8 hh, ll;
#pragma unroll
            for (int j = 0; j < 8; ++j) {
                const float f = xv[g * 8 + j];
                const unsigned short h = bf16_rne(f);
                hh[j] = (short)h;
                ll[j] = (short)bf16_rne(f - bf16_to_f(h));
            }
            const int d0 = dg * 16 + g * 8;
            const int pos = p * 64 + (d0 ^ ((p & 7) << 3));
            *(short8*)(xbh + pos) = hh;
            *(short8*)(xbl + pos) = ll;
        }
    }
    __syncthreads();   // x-bf16 + enh_lds visible to all waves

    const int ln15 = lane & 15, q8 = (lane >> 4) * 8;
    const int wp = wave * 16;          // this wave's 16 points (ALL codes)

    short8 ah[2], al[2];               // persistent A frags [kc] (16 VGPR)
#pragma unroll
    for (int kc = 0; kc < 2; ++kc) {
        const int pp = wp + ln15;
        const int pos = pp * 64 + ((kc * 32 + q8) ^ ((pp & 7) << 3));
        ah[kc] = *(const short8*)(xbh + pos);
        al[kc] = *(const short8*)(xbl + pos);
    }
    __syncthreads();   // frags in regs everywhere; ebuf free for tile DMA

    // per-wave DMA share: 2 x 1KB ops/tile. waves 0-3 -> hi 8KB, 4-7 -> lo 8KB
    const int wsel = (wave < 4) ? wave : (wave - 4);
    const char* srcTab = (wave < 4) ? ehTb : elTb;
    const int dofs = ((wave < 4) ? 0 : 8192) + wsel * 2048;

    // DMA(0) into buf0
    {
        const char* sb = srcTab + wsel * 2048 + lane * 16;
        gld_lds16(sb,        ebuf + dofs);
        gld_lds16(sb + 1024, ebuf + dofs + 1024);
    }

    unsigned v1u[4], v2u[4];
#pragma unroll
    for (int r = 0; r < 4; ++r) { v1u[r] = 0u; v2u[r] = 0u; }

    for (int kt = 0; kt < 16; ++kt) {
        __syncthreads();   // drains tile-kt DMA + all waves done with kt-1
        if (kt < 15) {     // stream tile kt+1 into the other buffer
            const int nkt = kt + 1;
            char* db = ebuf + (nkt & 1) * 16384;
            const char* sb = srcTab + nkt * 8192 + wsel * 2048 + lane * 16;
            gld_lds16(sb,        db + dofs);
            gld_lds16(sb + 1024, db + dofs + 1024);
        }
        const unsigned short* ebH = (const unsigned short*)(ebuf + (kt & 1) * 16384);
        const unsigned short* ebL = ebH + 4096;   // lo half at +8192B

        // acc init = 512 - ||e||^2/2 (biased argmax score)
        f32x4 acc[4];
#pragma unroll
        for (int cf = 0; cf < 4; ++cf) {
            const float ec = enh_lds[kt * 64 + cf * 16 + ln15];
            acc[cf] = (f32x4){ec, ec, ec, ec};
        }

#pragma unroll
        for (int kc = 0; kc < 2; ++kc) {
            short8 bh[4], bl[4];
#pragma unroll
            for (int cf = 0; cf < 4; ++cf) {
                const int c = cf * 16 + ln15;
                const int pos = c * 64 + ((kc * 32 + q8) ^ ((c & 7) << 3));
                bh[cf] = *(const short8*)(ebH + pos);
                bl[cf] = *(const short8*)(ebL + pos);
            }
#pragma unroll
            for (int cf = 0; cf < 4; ++cf) {
                acc[cf] = __builtin_amdgcn_mfma_f32_16x16x32_bf16(al[kc], bh[cf], acc[cf], 0, 0, 0);
                acc[cf] = __builtin_amdgcn_mfma_f32_16x16x32_bf16(ah[kc], bl[cf], acc[cf], 0, 0, 0);
                acc[cf] = __builtin_amdgcn_mfma_f32_16x16x32_bf16(ah[kc], bh[cf], acc[cf], 0, 0, 0);
            }
        }

        // packed-key top-2 per reg row: key = (bits|63) ^ (kt*4+cf)
        // (low6 = 63^col6 -> umax tie-breaks toward SMALLER col6 = smaller k)
#pragma unroll
        for (int reg = 0; reg < 4; ++reg) {
            const unsigned k0 = (__float_as_uint(acc[0][reg]) | 63u) ^ (unsigned)(kt * 4 + 0);
            const unsigned k1 = (__float_as_uint(acc[1][reg]) | 63u) ^ (unsigned)(kt * 4 + 1);
            const unsigned k2 = (__float_as_uint(acc[2][reg]) | 63u) ^ (unsigned)(kt * 4 + 2);
            const unsigned k3 = (__float_as_uint(acc[3][reg]) | 63u) ^ (unsigned)(kt * 4 + 3);
            unsigned a = umax(k0, k1), bb = umin(k0, k1);
            v2u[reg] = umax(umax(v2u[reg], umin(v1u[reg], a)), bb);
            v1u[reg] = umax(v1u[reg], a);
            a = umax(k2, k3); bb = umin(k2, k3);
            v2u[reg] = umax(umax(v2u[reg], umin(v1u[reg], a)), bb);
            v1u[reg] = umax(v1u[reg], a);
        }
    }

    __syncthreads();   // all waves done with tile 15 -> ebuf aliases safe
    if (tid == 0) *rn = 0;
    __syncthreads();

    // decode + cross-lane merge within the 16 lanes sharing each row-set.
    // Each wave covers ALL codes for its 16 pts -> result is final per point.
#pragma unroll
    for (int r = 0; r < 4; ++r) {
        const unsigned c6 = 63u - (v1u[r] & 63u);
        int col = (int)(c6 >> 2) * 64 + (int)(c6 & 3) * 16 + ln15;
        float val = __uint_as_float(v1u[r] & ~63u);
        float sec = __uint_as_float(v2u[r] & ~63u);
#pragma unroll
        for (int msk = 1; msk < 16; msk <<= 1) {
            const float ov = __shfl_xor(val, msk);
            const int oc = __shfl_xor(col, msk);
            const float os = __shfl_xor(sec, msk);
            sec = fmaxf(fmaxf(sec, os), fminf(val, ov));
            const bool t = (ov > val) || (ov == val && oc < col);
            val = t ? ov : val;
            col = t ? oc : col;
        }
        if (ln15 == 0) {
            const int qq = lane >> 4;
            const int pt = wp + qq * 4 + r;   // row = q*4 + reg (16x16 C layout)
            ks[pt] = col;
            if (val - sec < MARGIN_S) {   // ambiguous under granule+bf16x3 bound
                const int w = atomicAdd(rn, 1);
                rl[w] = pt;               // <=128 entries possible
            }
        }
    }
    __syncthreads();

    // ---- in-block exact fp32 rescue (cold: ~0.3 items/block) ----
    const int lcnt = *rn;
    for (int it = 0; it < lcnt; ++it) {
        const int pr = rl[it];
        if (tid < 64) xp[tid] = x[((b * DD + tid) << 12) + hw0 + pr];
        __syncthreads();
        float bs = -3.4e38f;
        int bi2 = 0;
        if (tid < 256) {   // 4 codes/thread over K=1024
            float d0 = 0.f, d1 = 0.f, d2 = 0.f, d3 = 0.f;
#pragma unroll 8
            for (int dd = 0; dd < DD; ++dd) {
                const float xd = xp[dd];
                const float4 ev = *(const float4*)(e + dd * KK + tid * 4);
                d0 = fmaf(xd, ev.x, d0);
                d1 = fmaf(xd, ev.y, d1);
                d2 = fmaf(xd, ev.z, d2);
                d3 = fmaf(xd, ev.w, d3);
            }
            const float4 ea = *(const float4*)(enh + tid * 4);
            bs = d0 + ea.x;
            bi2 = tid * 4;
            if (d1 + ea.y > bs) { bs = d1 + ea.y; bi2 = tid * 4 + 1; }
            if (d2 + ea.z > bs) { bs = d2 + ea.z; bi2 = tid * 4 + 2; }
            if (d3 + ea.w > bs) { bs = d3 + ea.w; bi2 = tid * 4 + 3; }
        }
#pragma unroll
        for (int m = 1; m < 64; m <<= 1) {
            const float ov = __shfl_xor(bs, m, 64);
            const int oi = __shfl_xor(bi2, m, 64);
            if (ov > bs || (ov == bs && oi < bi2)) { bs = ov; bi2 = oi; }
        }
        if (lane == 0) { rv[wave] = bs; ri[wave] = bi2; }
        __syncthreads();
        if (tid == 0) {
            float gs = rv[0];
            int gi = ri[0];
#pragma unroll
            for (int t2 = 1; t2 < 8; ++t2)
                if (rv[t2] > gs || (rv[t2] == gs && ri[t2] < gi)) { gs = rv[t2]; gi = ri[t2]; }
            ks[pr] = gi;
        }
        __syncthreads();
    }

    if (tid < 128) out[OFF_IDX + n0 + tid] = (float)ks[tid];

    // ---- quantize + loss epilogue (exact fp32; x re-read, e gathered) ----
    {
        const int pe = tid & 127, dh = tid >> 7;   // 16 d's per thread
        const int kp = ks[pe];
        float lacc = 0.f;
#pragma unroll
        for (int s = 0; s < 16; ++s) {
            const int d = dh * 16 + s;
            const float qv = e[d * KK + kp];
            const float xv = x[((b * DD + d) << 12) + hw0 + pe];
            out[((b * DD + d) << 12) + hw0 + pe] = qv;
            const float df = xv - qv;
            lacc = fmaf(df, df, lacc);
        }
#pragma unroll
        for (int off = 32; off > 0; off >>= 1) lacc += __shfl_down(lacc, off, 64);
        if (lane == 0) red[wave] = lacc;
    }
    __syncthreads();
    if (tid == 0) {
        float bsum = red[0];
#pragma unroll
        for (int w2 = 1; w2 < 8; ++w2) bsum += red[w2];
        atomicAdd(sum, bsum);
        __threadfence();
        const unsigned old = atomicAdd(tick, 1u);
        if (old == (unsigned)(NBLK_TOTAL - 1)) {
            const float s = atomicAdd(sum, 0.0f);
            const float m = s * (1.0f / (float)TOTAL);
            out[OFF_L1] = m;   // dictionary_loss
            out[OFF_L2] = m;   // commitment_loss (numerically identical)
        }
    }
}

extern "C" void kernel_launch(void* const* d_in, const int* in_sizes, int n_in,
                              void* d_out, int out_size, void* d_ws, size_t ws_size,
                              hipStream_t stream) {
    const float* x = (const float*)d_in[0];      // [16,64,64,64]
    const float* e = (const float*)d_in[1];      // [64,1024]
    float* out = (float*)d_out;

    float* sum = (float*)d_ws;
    unsigned* tick = (unsigned*)d_ws + 2;
    float* enh = (float*)d_ws + WS_ENH_F;
    unsigned short* ehT = (unsigned short*)((char*)d_ws + WS_EHT_BYTE);
    unsigned short* elT = (unsigned short*)((char*)d_ws + WS_ELT_BYTE);

    prep_kernel<<<KK / 64, 256, 0, stream>>>(e, enh, ehT, elT, sum, tick);
    vq_gemm<<<NPTS / 128, 512, 0, stream>>>(x, e, enh, ehT, elT, out, sum, tick);
}